// Round 15
// baseline (752.942 us; speedup 1.0000x reference)
//
#include <hip/hip_runtime.h>
#include <cstdint>

#define N_NODES 49152
#define DIM 512
#define NH 8
#define DHEAD 64
#define NE 131072
#define ETOT (NE + N_NODES)   /* 180224 */
#define NLAYERS 5
#define AGG_NODES 32          /* nodes per gat_agg block (8 waves x 4) */
#define AGG_BLOCKS (N_NODES / AGG_NODES)   /* 1536 */

typedef short short8 __attribute__((ext_vector_type(8)));
typedef float floatx4 __attribute__((ext_vector_type(4)));

__device__ __forceinline__ float bf2f(unsigned short v) {
  union { unsigned int u; float f; } x; x.u = ((unsigned int)v) << 16; return x.f;
}
__device__ __forceinline__ unsigned short f2bf(float f) {
  union { float f; unsigned int u; } x; x.f = f;
  unsigned int r = x.u + 0x7fffu + ((x.u >> 16) & 1u);
  return (unsigned short)(r >> 16);
}
__device__ __forceinline__ void async_load16(const void* g, void* l) {
  __builtin_amdgcn_global_load_lds((const __attribute__((address_space(1))) void*)g,
                                   (__attribute__((address_space(3))) void*)l, 16, 0, 0);
}

// ---------------- W transpose + convert: WT[l][n][k] = bf16(Ws[l][k][n]) ----------------
__global__ void transpose_w_r22(const float* __restrict__ Ws, unsigned short* __restrict__ WT)
{
  __shared__ float tile[32][33];
  const int l  = blockIdx.z;
  const int nt = blockIdx.x * 32, kt = blockIdx.y * 32;
  const int tx = threadIdx.x & 31, ty = threadIdx.x >> 5;   // 256 threads
  #pragma unroll
  for (int r = 0; r < 32; r += 8)
    tile[ty + r][tx] = Ws[(size_t)l*DIM*DIM + (size_t)(kt + ty + r)*DIM + nt + tx];
  __syncthreads();
  #pragma unroll
  for (int r = 0; r < 32; r += 8)
    WT[(size_t)l*DIM*DIM + (size_t)(nt + ty + r)*DIM + kt + tx] = f2bf(tile[tx][ty + r]);
}

// ---------------- edge index canonicalize (auto-detect int64 vs int32) ----------------
__global__ void repack_edges_r22(const int* __restrict__ raw, int* __restrict__ eidx)
{
  const int i = blockIdx.x * 256 + threadIdx.x;    // 2*NE threads
  bool is64 = true;
  #pragma unroll
  for (int j = 0; j < 16; j++) is64 = is64 && (raw[2*j + 1] == 0);
  int v;
  if (is64) v = (int)((const long long*)raw)[i];
  else      v = raw[i];
  eidx[i] = v;
}

// ---------------- CSR build ----------------
__global__ void init_counts_r22(int* __restrict__ counts) {
  counts[blockIdx.x * 256 + threadIdx.x] = 1;    // self-loop
}
__global__ void hist_dst_r22(const int* __restrict__ eidx, int* __restrict__ counts) {
  const int i = blockIdx.x * 256 + threadIdx.x;  // NE threads
  atomicAdd(&counts[eidx[NE + i]], 1);
}
__global__ void scan_kernel_r22(const int* __restrict__ counts, int* __restrict__ offs, int* __restrict__ cursor)
{
  __shared__ int tot[1024];
  const int t = threadIdx.x;
  const int base = t * 48;                       // N_NODES = 1024*48
  int s = 0;
  for (int i = 0; i < 48; i++) s += counts[base + i];
  tot[t] = s;
  __syncthreads();
  for (int o = 1; o < 1024; o <<= 1) {
    int v = (t >= o) ? tot[t - o] : 0;
    __syncthreads();
    tot[t] += v;
    __syncthreads();
  }
  int run = tot[t] - s;
  for (int i = 0; i < 48; i++) {
    offs[base + i] = run;
    cursor[base + i] = run;
    run += counts[base + i];
  }
  if (t == 1023) offs[N_NODES] = tot[1023];
}
__global__ void scatter_edges_r22(const int* __restrict__ eidx, int* __restrict__ cursor, int* __restrict__ csrc)
{
  const int i = blockIdx.x * 256 + threadIdx.x;  // ETOT threads
  int s, d;
  if (i < NE) { s = eidx[i]; d = eidx[NE + i]; }
  else        { s = i - NE; d = s; }
  const int pos = atomicAdd(&cursor[d], 1);
  csrc[pos] = s;
}

// ---------------- zero the BN stat accumulators (before layer 0) ----------------
__global__ void zero_acc_r22(float* __restrict__ ssum, float* __restrict__ sqsum)
{
  const int t = threadIdx.x;        // 512 threads, 1 block
  ssum[t] = 0.f;
  sqsum[t] = 0.f;
}

// ---------------- GEMM 128m x 256n (8 waves), r20 structure; pairing per-layer ----------------
// pair==1 (layers 1-4): XCD A-panel pairing — m = (d&7)*48 + (d>>3)/2, n = (d>>3)&1.
// pair==0 (layer 0, fp32 A): plain mapping (pairing measured +7us on the fp32-A layer).
// A-operand modes (both bit-exact vs the old separate passes):
//   Af != null : layer 0 — reg-staged fp32 -> f2bf
//   bnscale != null : layers 1-4 — reg-staged BN+relu from bf16
// B via global_load_lds with pre-swizzled source columns.
// LDS XOR-8 swizzle in 16B groups (colgrp ^ row&7) on both tiles (0 conflicts measured).
__global__ __launch_bounds__(512, 4) void gemm_bt_r22(const float* __restrict__ Af,
                                                      const unsigned short* __restrict__ Ab,
                                                      const unsigned short* __restrict__ BT,
                                                      const float* __restrict__ asrc,
                                                      const float* __restrict__ adst,
                                                      const float* __restrict__ bnscale,
                                                      const float* __restrict__ bnshift,
                                                      unsigned short* __restrict__ C,
                                                      float* __restrict__ als,
                                                      float* __restrict__ ald,
                                                      int pair)
{
  __shared__ unsigned short As[128 * 64];   // 16 KiB
  __shared__ unsigned short Bs[256 * 64];   // 32 KiB
  const int d = blockIdx.x;                 // 0..767
  int m_blk, n_blk;
  if (pair) {
    m_blk = (d & 7) * 48 + ((d >> 3) >> 1);
    n_blk = (d >> 3) & 1;
  } else {
    n_blk = (d >= 384) ? 1 : 0;
    m_blk = d - n_blk * 384;
  }
  const int m0 = m_blk * 128;
  const int n0 = n_blk * 256;
  const int tid = threadIdx.x;
  const int wv = tid >> 6, lane = tid & 63;         // 8 waves
  const int wr = (wv & 1) * 64, wc = (wv >> 1) * 64; // m 2 x n 4
  const int q = lane >> 4, c16 = lane & 15;
  const int arow = lane >> 3;          // 0..7 within an 8-row chunk
  // pre-swizzled k offset for async loads: colgrp (lane&7) XOR row (arow)
  const int acol = (((lane & 7) ^ arow) * 8);
  // reg-staged A map: thread -> (row, k) ; 512 threads cover 64 rows x 64 k, x2 row-halves
  const int sr = tid >> 3;             // 0..63
  const int sk = (tid & 7) * 8;        // 0..56  (data column)
  const int swk = (((tid & 7) ^ (sr & 7)) * 8);   // swizzled LDS column
  // fragment-read swizzle
  const int rx = (c16 & 7);
  const bool isconv = (Af != nullptr);

  floatx4 acc[4][4] = {};

  for (int k0 = 0; k0 < DIM; k0 += 64) {
    #pragma unroll
    for (int t = 0; t < 4; t++) {      // B: 32 chunks (issue first, stays in flight)
      const int cb = wv * 4 + t;
      async_load16(BT + (size_t)(n0 + cb*8 + arow)*DIM + k0 + acol, &Bs[cb * 512]);
    }
    if (isconv) {
      // fused fp32->bf16 A staging (replaces convert_x; bit-exact f2bf)
      #pragma unroll
      for (int t = 0; t < 2; t++) {
        const float4 v0 = *(const float4*)&Af[(size_t)(m0 + sr + t*64) * DIM + k0 + sk];
        const float4 v1 = *(const float4*)&Af[(size_t)(m0 + sr + t*64) * DIM + k0 + sk + 4];
        const float v[8] = {v0.x, v0.y, v0.z, v0.w, v1.x, v1.y, v1.z, v1.w};
        unsigned int ov[4];
        #pragma unroll
        for (int j = 0; j < 4; j++)
          ov[j] = (unsigned int)f2bf(v[2*j]) | ((unsigned int)f2bf(v[2*j+1]) << 16);
        *(uint4*)&As[(sr + t*64) * 64 + swk] = *(const uint4*)ov;
      }
    } else if (bnscale) {
      // fused BN+relu A staging (reg-staged; swizzled ds_write)
      const uint4 x0 = *(const uint4*)&Ab[(size_t)(m0 + sr)      * DIM + k0 + sk];
      const uint4 x1 = *(const uint4*)&Ab[(size_t)(m0 + sr + 64) * DIM + k0 + sk];
      const float4 sc0 = *(const float4*)&bnscale[k0 + sk];
      const float4 sc1 = *(const float4*)&bnscale[k0 + sk + 4];
      const float4 sh0 = *(const float4*)&bnshift[k0 + sk];
      const float4 sh1 = *(const float4*)&bnshift[k0 + sk + 4];
      const float scv[8] = {sc0.x, sc0.y, sc0.z, sc0.w, sc1.x, sc1.y, sc1.z, sc1.w};
      const float shv[8] = {sh0.x, sh0.y, sh0.z, sh0.w, sh1.x, sh1.y, sh1.z, sh1.w};
      const uint4 xs[2] = {x0, x1};
      #pragma unroll
      for (int t = 0; t < 2; t++) {
        const unsigned int* xp = (const unsigned int*)&xs[t];
        unsigned int ov[4];
        #pragma unroll
        for (int j = 0; j < 4; j++) {
          const float a = bf2f((unsigned short)(xp[j] & 0xffffu));
          const float b = bf2f((unsigned short)(xp[j] >> 16));
          const float ya = fmaxf(0.f, a * scv[2*j]     + shv[2*j]);
          const float yb = fmaxf(0.f, b * scv[2*j + 1] + shv[2*j + 1]);
          ov[j] = (unsigned int)f2bf(ya) | ((unsigned int)f2bf(yb) << 16);
        }
        *(uint4*)&As[(sr + t*64) * 64 + swk] = *(const uint4*)ov;
      }
    } else {
      #pragma unroll
      for (int t = 0; t < 2; t++) {    // A raw: async path (pre-swizzled source)
        const int cb = wv * 2 + t;
        async_load16(Ab + (size_t)(m0 + cb*8 + arow)*DIM + k0 + acol, &As[cb * 512]);
      }
    }
    __syncthreads();
    #pragma unroll
    for (int kk = 0; kk < 64; kk += 32) {
      const int cg = (kk >> 3) + q;                 // data colgrp 0..7
      const int po = ((cg ^ rx) * 8);               // physical bf16 offset
      short8 aF[4], bF[4];
      #pragma unroll
      for (int mt = 0; mt < 4; mt++)
        aF[mt] = *(const short8*)&As[(wr + mt*16 + c16) * 64 + po];
      #pragma unroll
      for (int nt = 0; nt < 4; nt++)
        bF[nt] = *(const short8*)&Bs[(wc + nt*16 + c16) * 64 + po];
      #pragma unroll
      for (int mt = 0; mt < 4; mt++)
        #pragma unroll
        for (int nt = 0; nt < 4; nt++)
          acc[mt][nt] = __builtin_amdgcn_mfma_f32_16x16x32_bf16(aF[mt], bF[nt], acc[mt][nt], 0, 0, 0);
    }
    __syncthreads();
  }
  // C/D layout (verified m89/m91): col = lane&15, row = (lane>>4)*4 + reg
  #pragma unroll
  for (int mt = 0; mt < 4; mt++) {
    #pragma unroll
    for (int nt = 0; nt < 4; nt++) {
      const int col = n0 + wc + nt*16 + c16;
      #pragma unroll
      for (int r = 0; r < 4; r++) {
        const int row = m0 + wr + mt*16 + q*4 + r;
        C[(size_t)row * DIM + col] = f2bf(acc[mt][nt][r]);
      }
    }
  }
  // fused logits: this wave's head covers cols [wc, wc+64) of this n-tile
  const int head = 4 * n_blk + (wc >> 6);
  float as_[4], ad_[4];
  #pragma unroll
  for (int nt = 0; nt < 4; nt++) {
    const int d2 = nt * 16 + c16;                // 0..63 within head
    as_[nt] = asrc[head * DHEAD + d2];
    ad_[nt] = adst[head * DHEAD + d2];
  }
  #pragma unroll
  for (int mt = 0; mt < 4; mt++) {
    #pragma unroll
    for (int r = 0; r < 4; r++) {
      float ss = 0.f, sd = 0.f;
      #pragma unroll
      for (int nt = 0; nt < 4; nt++) {
        ss += acc[mt][nt][r] * as_[nt];
        sd += acc[mt][nt][r] * ad_[nt];
      }
      #pragma unroll
      for (int msk = 1; msk <= 8; msk <<= 1) {   // reduce over the 16 c16 lanes
        ss += __shfl_xor(ss, msk, 64);
        sd += __shfl_xor(sd, msk, 64);
      }
      if (c16 == 0) {
        const int row = m0 + wr + mt*16 + q*4 + r;
        als[row * NH + head] = ss;
        ald[row * NH + head] = sd;
      }
    }
  }
}

// ---------------- GAT aggregate r22: r21 structure, BN partials via atomicAdd ----------------
// Change vs r21: per-block column partials are atomically accumulated into global
// ssum/sqsum[512] (2 atomicAdds/thread; ~1536 adds/address spread over the whole
// kernel -> no contention) instead of writing 6.3 MB of per-block ps/pq arrays.
__global__ __launch_bounds__(512, 4) void gat_agg_r22(const unsigned short* __restrict__ Hm,
    const float* __restrict__ als, const float* __restrict__ ald,
    const int* __restrict__ offs, const int* __restrict__ csrc,
    const float* __restrict__ bconv, unsigned short* __restrict__ Xout,
    float* __restrict__ ssum, float* __restrict__ sqsum)
{
  __shared__ float red[8][1024];
  const int wv = threadIdx.x >> 6, lane = threadIdx.x & 63;
  const int hd = lane >> 3;            // head owning dims [lane*8, lane*8+8)
  const int hp = lane & 7;             // head in the parallel-logit mapping
  const int slot = lane >> 3;          // edge slot in the parallel-logit mapping
  const float4 bA = ((const float4*)(bconv + (size_t)lane * 8))[0];
  const float4 bB = ((const float4*)(bconv + (size_t)lane * 8))[1];
  const float barr[8] = {bA.x, bA.y, bA.z, bA.w, bB.x, bB.y, bB.z, bB.w};
  float cs[8] = {}, cq[8] = {};

  #pragma unroll 2
  for (int i = 0; i < 4; i++) {
    const int node = blockIdx.x * AGG_NODES + wv * 4 + i;
    const int e0 = offs[node], e1 = offs[node + 1];
    const int deg = e1 - e0;
    float acc[8] = {};
    float zinv;

    if (deg <= 8) {
      // ---- hot path ----
      const float aldp = ald[node * NH + hp];
      const int myS = csrc[e0 + ((lane < deg) ? lane : 0)];
      const int s_slot = __shfl(myS, slot, 64);
      float lg = als[s_slot * NH + hp] + aldp;
      lg = lg > 0.f ? lg : 0.2f * lg;
      const float lgv = (slot < deg) ? lg : -1e30f;
      float mx = fmaxf(lgv, __shfl_xor(lgv, 8, 64));
      mx = fmaxf(mx, __shfl_xor(mx, 16, 64));
      mx = fmaxf(mx, __shfl_xor(mx, 32, 64));
      const float w = __expf(lgv - mx);            // pad slots: 0
      float z = w + __shfl_xor(w, 8, 64);
      z += __shfl_xor(z, 16, 64);
      z += __shfl_xor(z, 32, 64);
      zinv = 1.f / (__shfl(z, hd, 64) + 1e-16f);

      #pragma unroll
      for (int g = 0; g < 2; g++) {
        const int b = g * 4;
        if (b < deg) {                              // wave-uniform guard
          const int k1 = (b+1 < deg) ? b+1 : 0;
          const int k2 = (b+2 < deg) ? b+2 : 0;
          const int k3 = (b+3 < deg) ? b+3 : 0;
          const int s0 = __shfl(myS, b,  64);
          const int s1 = __shfl(myS, k1, 64);
          const int s2 = __shfl(myS, k2, 64);
          const int s3 = __shfl(myS, k3, 64);
          const uint4 h0v = *(const uint4*)&Hm[(size_t)s0 * DIM + lane * 8];
          const uint4 h1v = *(const uint4*)&Hm[(size_t)s1 * DIM + lane * 8];
          const uint4 h2v = *(const uint4*)&Hm[(size_t)s2 * DIM + lane * 8];
          const uint4 h3v = *(const uint4*)&Hm[(size_t)s3 * DIM + lane * 8];
          const float w0 = __shfl(w, (b+0)*8 + hd, 64);
          const float w1 = __shfl(w, (b+1)*8 + hd, 64);  // 0 if b+1 >= deg
          const float w2 = __shfl(w, (b+2)*8 + hd, 64);
          const float w3 = __shfl(w, (b+3)*8 + hd, 64);
          const unsigned int* p0 = (const unsigned int*)&h0v;
          const unsigned int* p1 = (const unsigned int*)&h1v;
          const unsigned int* p2 = (const unsigned int*)&h2v;
          const unsigned int* p3 = (const unsigned int*)&h3v;
          #pragma unroll
          for (int j = 0; j < 4; j++) {
            acc[2*j]   += w0 * bf2f((unsigned short)(p0[j] & 0xffffu))
                        + w1 * bf2f((unsigned short)(p1[j] & 0xffffu))
                        + w2 * bf2f((unsigned short)(p2[j] & 0xffffu))
                        + w3 * bf2f((unsigned short)(p3[j] & 0xffffu));
            acc[2*j+1] += w0 * bf2f((unsigned short)(p0[j] >> 16))
                        + w1 * bf2f((unsigned short)(p1[j] >> 16))
                        + w2 * bf2f((unsigned short)(p2[j] >> 16))
                        + w3 * bf2f((unsigned short)(p3[j] >> 16));
          }
        }
      }
    } else if (deg <= 64) {
      // ---- mid path (rare, ~0.6%) ----
      const float aldp = ald[node * NH + hp];
      const int myS = (lane < deg) ? csrc[e0 + lane] : 0;
      const int nr = (deg + 7) >> 3;
      float lgsto[8];
      #pragma unroll
      for (int r = 0; r < 8; r++) {
        if (r < nr) {
          const int k = r * 8 + slot;
          const int s = __shfl(myS, k & 63, 64);
          float lg = als[s * NH + hp] + aldp;
          lg = lg > 0.f ? lg : 0.2f * lg;
          lgsto[r] = (k < deg) ? lg : -1e30f;
        } else lgsto[r] = -1e30f;
      }
      float m = lgsto[0];
      #pragma unroll
      for (int r = 1; r < 8; r++) m = fmaxf(m, lgsto[r]);
      m = fmaxf(m, __shfl_xor(m, 8, 64));
      m = fmaxf(m, __shfl_xor(m, 16, 64));
      m = fmaxf(m, __shfl_xor(m, 32, 64));
      float z = 0.f;
      float wsto[8];
      #pragma unroll
      for (int r = 0; r < 8; r++) {
        if (r < nr) {
          const float w = __expf(lgsto[r] - m);
          wsto[r] = w; z += w;
        } else wsto[r] = 0.f;
      }
      z += __shfl_xor(z, 8, 64);
      z += __shfl_xor(z, 16, 64);
      z += __shfl_xor(z, 32, 64);
      zinv = 1.f / (__shfl(z, hd, 64) + 1e-16f);

      int sn = __shfl(myS, 0, 64);
      uint4 hv = *(const uint4*)&Hm[(size_t)sn * DIM + lane * 8];
      #pragma unroll
      for (int r = 0; r < 8; r++) {
        if (r * 8 < deg) {
          const int kmax = (deg - r * 8 < 8) ? (deg - r * 8) : 8;
          for (int kk = 0; kk < kmax; kk++) {
            const uint4 hcur = hv;
            const int k = r * 8 + kk;
            if (k + 1 < deg) {
              const int s2 = __shfl(myS, (k + 1) & 63, 64);
              hv = *(const uint4*)&Hm[(size_t)s2 * DIM + lane * 8];
            }
            const float w = __shfl(wsto[r], (kk << 3) + hd, 64);
            const unsigned int* hpx = (const unsigned int*)&hcur;
            #pragma unroll
            for (int j = 0; j < 4; j++) {
              acc[2*j]   += w * bf2f((unsigned short)(hpx[j] & 0xffffu));
              acc[2*j+1] += w * bf2f((unsigned short)(hpx[j] >> 16));
            }
          }
        }
      }
    } else {
      // ---- generic fallback (deg > 64): online softmax ----
      const float aldv = ald[node * NH + hd];
      float m = -1e30f, z = 0.f;
      for (int e = e0; e < e1; e++) {
        const int s = csrc[e];
        float lg = als[s * NH + hd] + aldv;
        lg = lg > 0.f ? lg : 0.2f * lg;
        const float mn = fmaxf(m, lg);
        const float sf = __expf(m - mn);
        const float w  = __expf(lg - mn);
        z = z * sf + w;
        const uint4 hv = *(const uint4*)&Hm[(size_t)s * DIM + lane * 8];
        const unsigned int* hpx = (const unsigned int*)&hv;
        #pragma unroll
        for (int j = 0; j < 4; j++) {
          acc[2*j]   = acc[2*j]   * sf + w * bf2f((unsigned short)(hpx[j] & 0xffffu));
          acc[2*j+1] = acc[2*j+1] * sf + w * bf2f((unsigned short)(hpx[j] >> 16));
        }
        m = mn;
      }
      zinv = 1.f / (z + 1e-16f);
    }

    unsigned int ov[4];
    #pragma unroll
    for (int j = 0; j < 4; j++) {
      const unsigned short b0 = f2bf(acc[2*j] * zinv + barr[2*j]);
      const unsigned short b1 = f2bf(acc[2*j+1] * zinv + barr[2*j+1]);
      ov[j] = (unsigned int)b0 | ((unsigned int)b1 << 16);
      const float y0 = bf2f(b0), y1 = bf2f(b1);   // rounded values, matching bn_stats-on-xbuf
      cs[2*j]   += y0; cq[2*j]   += y0 * y0;
      cs[2*j+1] += y1; cq[2*j+1] += y1 * y1;
    }
    *(uint4*)&Xout[(size_t)node * DIM + lane * 8] = *(const uint4*)ov;
  }
  #pragma unroll
  for (int j = 0; j < 8; j++) {
    red[wv][lane * 8 + j] = cs[j];
    red[wv][512 + lane * 8 + j] = cq[j];
  }
  __syncthreads();
  const int t = threadIdx.x;          // 0..511 -> one column each
  float s = 0.f, q = 0.f;
  #pragma unroll
  for (int w = 0; w < 8; w++) {
    s += red[w][t];
    q += red[w][512 + t];
  }
  atomicAdd(&ssum[t], s);
  atomicAdd(&sqsum[t], q);
}

// ---------------- BN finalize: 1 block; compute scale/shift, re-zero accumulators ----------------
__global__ __launch_bounds__(512) void bn_finalize_r22(float* __restrict__ ssum, float* __restrict__ sqsum,
                                                       const float* __restrict__ gamma, const float* __restrict__ beta,
                                                       float* __restrict__ scale, float* __restrict__ shift)
{
  const int c = threadIdx.x;          // 0..511
  const float inv = 1.0f / (float)N_NODES;
  const float mean = ssum[c] * inv;
  float var = sqsum[c] * inv - mean * mean;
  var = fmaxf(var, 0.f);
  const float rsq = rsqrtf(var + 1e-5f);
  const float sc = gamma[c] * rsq;
  scale[c] = sc;
  shift[c] = beta[c] - mean * sc;
  ssum[c] = 0.f;                      // ready for next layer's gat_agg
  sqsum[c] = 0.f;
}

// ---------------- final head: out[n] = relu(bn(X[n,:])) . Wl + bl ----------------
__global__ __launch_bounds__(256) void final_head_r22(const unsigned short* __restrict__ X,
    const float* __restrict__ scale, const float* __restrict__ shift,
    const float* __restrict__ wl, const float* __restrict__ blp,
    float* __restrict__ out)
{
  const int wv = threadIdx.x >> 6, lane = threadIdx.x & 63;
  const int node = blockIdx.x * 4 + wv;
  const uint4 xv = *(const uint4*)&X[(size_t)node * DIM + lane * 8];
  const unsigned int* xp = (const unsigned int*)&xv;
  const int c0 = lane * 8;
  float s = 0.f;
  #pragma unroll
  for (int i = 0; i < 4; i++) {
    const float a0 = bf2f((unsigned short)(xp[i] & 0xffffu));
    const float a1 = bf2f((unsigned short)(xp[i] >> 16));
    const float y0 = fmaxf(0.f, a0 * scale[c0 + 2*i]     + shift[c0 + 2*i]);
    const float y1 = fmaxf(0.f, a1 * scale[c0 + 2*i + 1] + shift[c0 + 2*i + 1]);
    s += y0 * wl[c0 + 2*i] + y1 * wl[c0 + 2*i + 1];
  }
  #pragma unroll
  for (int msk = 32; msk >= 1; msk >>= 1) s += __shfl_xor(s, msk, 64);
  if (lane == 0) out[node] = s + blp[0];
}

extern "C" void kernel_launch(void* const* d_in, const int* in_sizes, int n_in,
                              void* d_out, int out_size, void* d_ws, size_t ws_size,
                              hipStream_t stream)
{
  const float* x_in  = (const float*)d_in[0];
  const int*   ei    = (const int*)d_in[1];
  const float* Ws    = (const float*)d_in[2];
  const float* Asrc  = (const float*)d_in[3];
  const float* Adst  = (const float*)d_in[4];
  const float* Bconv = (const float*)d_in[5];
  const float* Gamma = (const float*)d_in[6];
  const float* Beta  = (const float*)d_in[7];
  const float* Wl    = (const float*)d_in[8];
  const float* bl    = (const float*)d_in[9];
  float* out = (float*)d_out;

  char* ws = (char*)d_ws;
  size_t off = 0;
  auto alloc = [&](size_t b) { char* p = ws + off; off += (b + 255) & ~(size_t)255; return p; };
  unsigned short* xbuf = (unsigned short*)alloc((size_t)N_NODES * DIM * 2);
  unsigned short* hbuf = (unsigned short*)alloc((size_t)N_NODES * DIM * 2);
  unsigned short* WT   = (unsigned short*)alloc((size_t)NLAYERS * DIM * DIM * 2);
  float* als   = (float*)alloc((size_t)N_NODES * NH * 4);
  float* ald   = (float*)alloc((size_t)N_NODES * NH * 4);
  int* eidx    = (int*)alloc((size_t)2 * NE * 4);
  int* counts  = (int*)alloc((size_t)N_NODES * 4);
  int* offs    = (int*)alloc(((size_t)N_NODES + 1) * 4);
  int* cursor  = (int*)alloc((size_t)N_NODES * 4);
  int* csrc    = (int*)alloc((size_t)ETOT * 4);
  float* ssum  = (float*)alloc(512 * 4);
  float* sqsum = (float*)alloc(512 * 4);
  float* scale = (float*)alloc(512 * 4);
  float* shift = (float*)alloc(512 * 4);

  transpose_w_r22<<<dim3(16, 16, 5), 256, 0, stream>>>(Ws, WT);
  repack_edges_r22<<<(2 * NE) / 256, 256, 0, stream>>>(ei, eidx);
  init_counts_r22<<<N_NODES / 256, 256, 0, stream>>>(counts);
  hist_dst_r22<<<NE / 256, 256, 0, stream>>>(eidx, counts);
  scan_kernel_r22<<<1, 1024, 0, stream>>>(counts, offs, cursor);
  scatter_edges_r22<<<ETOT / 256, 256, 0, stream>>>(eidx, cursor, csrc);
  zero_acc_r22<<<1, 512, 0, stream>>>(ssum, sqsum);

  for (int l = 0; l < NLAYERS; l++) {
    gemm_bt_r22<<<768, 512, 0, stream>>>(
        (l == 0) ? x_in : nullptr, (l == 0) ? nullptr : xbuf,
        WT + (size_t)l * DIM * DIM,
        Asrc + l * NH * DHEAD, Adst + l * NH * DHEAD,
        (l == 0) ? nullptr : scale, (l == 0) ? nullptr : shift,
        hbuf, als, ald, (l == 0) ? 0 : 1);
    gat_agg_r22<<<AGG_BLOCKS, 512, 0, stream>>>(hbuf, als, ald, offs, csrc,
                                                Bconv + l * DIM, xbuf, ssum, sqsum);
    bn_finalize_r22<<<1, 512, 0, stream>>>(ssum, sqsum, Gamma + l * DIM, Beta + l * DIM, scale, shift);
  }
  final_head_r22<<<N_NODES / 4, 256, 0, stream>>>(xbuf, scale, shift, Wl, bl, out);
}

// Round 16
// 718.872 us; speedup vs baseline: 1.0474x; 1.0474x over previous
//
#include <hip/hip_runtime.h>
#include <cstdint>

#define N_NODES 49152
#define DIM 512
#define NH 8
#define DHEAD 64
#define NE 131072
#define ETOT (NE + N_NODES)   /* 180224 */
#define NLAYERS 5
#define AGG_NODES 32          /* nodes per gat_agg block (8 waves x 4) */
#define AGG_BLOCKS (N_NODES / AGG_NODES)   /* 1536 */

typedef short short8 __attribute__((ext_vector_type(8)));
typedef float floatx4 __attribute__((ext_vector_type(4)));

__device__ __forceinline__ float bf2f(unsigned short v) {
  union { unsigned int u; float f; } x; x.u = ((unsigned int)v) << 16; return x.f;
}
__device__ __forceinline__ unsigned short f2bf(float f) {
  union { float f; unsigned int u; } x; x.f = f;
  unsigned int r = x.u + 0x7fffu + ((x.u >> 16) & 1u);
  return (unsigned short)(r >> 16);
}
__device__ __forceinline__ void async_load16(const void* g, void* l) {
  __builtin_amdgcn_global_load_lds((const __attribute__((address_space(1))) void*)g,
                                   (__attribute__((address_space(3))) void*)l, 16, 0, 0);
}

// ---------------- W transpose + convert: WT[l][n][k] = bf16(Ws[l][k][n]) ----------------
__global__ void transpose_w_r23(const float* __restrict__ Ws, unsigned short* __restrict__ WT)
{
  __shared__ float tile[32][33];
  const int l  = blockIdx.z;
  const int nt = blockIdx.x * 32, kt = blockIdx.y * 32;
  const int tx = threadIdx.x & 31, ty = threadIdx.x >> 5;   // 256 threads
  #pragma unroll
  for (int r = 0; r < 32; r += 8)
    tile[ty + r][tx] = Ws[(size_t)l*DIM*DIM + (size_t)(kt + ty + r)*DIM + nt + tx];
  __syncthreads();
  #pragma unroll
  for (int r = 0; r < 32; r += 8)
    WT[(size_t)l*DIM*DIM + (size_t)(nt + ty + r)*DIM + kt + tx] = f2bf(tile[tx][ty + r]);
}

// ---------------- edge index canonicalize (auto-detect int64 vs int32) ----------------
__global__ void repack_edges_r23(const int* __restrict__ raw, int* __restrict__ eidx)
{
  const int i = blockIdx.x * 256 + threadIdx.x;    // 2*NE threads
  bool is64 = true;
  #pragma unroll
  for (int j = 0; j < 16; j++) is64 = is64 && (raw[2*j + 1] == 0);
  int v;
  if (is64) v = (int)((const long long*)raw)[i];
  else      v = raw[i];
  eidx[i] = v;
}

// ---------------- CSR build ----------------
__global__ void init_counts_r23(int* __restrict__ counts) {
  counts[blockIdx.x * 256 + threadIdx.x] = 1;    // self-loop
}
__global__ void hist_dst_r23(const int* __restrict__ eidx, int* __restrict__ counts) {
  const int i = blockIdx.x * 256 + threadIdx.x;  // NE threads
  atomicAdd(&counts[eidx[NE + i]], 1);
}
__global__ void scan_kernel_r23(const int* __restrict__ counts, int* __restrict__ offs, int* __restrict__ cursor)
{
  __shared__ int tot[1024];
  const int t = threadIdx.x;
  const int base = t * 48;                       // N_NODES = 1024*48
  int s = 0;
  for (int i = 0; i < 48; i++) s += counts[base + i];
  tot[t] = s;
  __syncthreads();
  for (int o = 1; o < 1024; o <<= 1) {
    int v = (t >= o) ? tot[t - o] : 0;
    __syncthreads();
    tot[t] += v;
    __syncthreads();
  }
  int run = tot[t] - s;
  for (int i = 0; i < 48; i++) {
    offs[base + i] = run;
    cursor[base + i] = run;
    run += counts[base + i];
  }
  if (t == 1023) offs[N_NODES] = tot[1023];
}
__global__ void scatter_edges_r23(const int* __restrict__ eidx, int* __restrict__ cursor, int* __restrict__ csrc)
{
  const int i = blockIdx.x * 256 + threadIdx.x;  // ETOT threads
  int s, d;
  if (i < NE) { s = eidx[i]; d = eidx[NE + i]; }
  else        { s = i - NE; d = s; }
  const int pos = atomicAdd(&cursor[d], 1);
  csrc[pos] = s;
}

// ---------------- GEMM 128m x 256n (8 waves), r20 structure; pairing per-layer ----------------
// pair==1 (layers 1-4): XCD A-panel pairing — m = (d&7)*48 + (d>>3)/2, n = (d>>3)&1.
// pair==0 (layer 0, fp32 A): plain mapping (pairing measured +7us on the fp32-A layer).
// A-operand modes (both bit-exact vs the old separate passes):
//   Af != null : layer 0 — reg-staged fp32 -> f2bf
//   bnscale != null : layers 1-4 — reg-staged BN+relu from bf16
// B via global_load_lds with pre-swizzled source columns.
// LDS XOR-8 swizzle in 16B groups (colgrp ^ row&7) on both tiles (0 conflicts measured).
__global__ __launch_bounds__(512, 4) void gemm_bt_r23(const float* __restrict__ Af,
                                                      const unsigned short* __restrict__ Ab,
                                                      const unsigned short* __restrict__ BT,
                                                      const float* __restrict__ asrc,
                                                      const float* __restrict__ adst,
                                                      const float* __restrict__ bnscale,
                                                      const float* __restrict__ bnshift,
                                                      unsigned short* __restrict__ C,
                                                      float* __restrict__ als,
                                                      float* __restrict__ ald,
                                                      int pair)
{
  __shared__ unsigned short As[128 * 64];   // 16 KiB
  __shared__ unsigned short Bs[256 * 64];   // 32 KiB
  const int d = blockIdx.x;                 // 0..767
  int m_blk, n_blk;
  if (pair) {
    m_blk = (d & 7) * 48 + ((d >> 3) >> 1);
    n_blk = (d >> 3) & 1;
  } else {
    n_blk = (d >= 384) ? 1 : 0;
    m_blk = d - n_blk * 384;
  }
  const int m0 = m_blk * 128;
  const int n0 = n_blk * 256;
  const int tid = threadIdx.x;
  const int wv = tid >> 6, lane = tid & 63;         // 8 waves
  const int wr = (wv & 1) * 64, wc = (wv >> 1) * 64; // m 2 x n 4
  const int q = lane >> 4, c16 = lane & 15;
  const int arow = lane >> 3;          // 0..7 within an 8-row chunk
  // pre-swizzled k offset for async loads: colgrp (lane&7) XOR row (arow)
  const int acol = (((lane & 7) ^ arow) * 8);
  // reg-staged A map: thread -> (row, k) ; 512 threads cover 64 rows x 64 k, x2 row-halves
  const int sr = tid >> 3;             // 0..63
  const int sk = (tid & 7) * 8;        // 0..56  (data column)
  const int swk = (((tid & 7) ^ (sr & 7)) * 8);   // swizzled LDS column
  // fragment-read swizzle
  const int rx = (c16 & 7);
  const bool isconv = (Af != nullptr);

  floatx4 acc[4][4] = {};

  for (int k0 = 0; k0 < DIM; k0 += 64) {
    #pragma unroll
    for (int t = 0; t < 4; t++) {      // B: 32 chunks (issue first, stays in flight)
      const int cb = wv * 4 + t;
      async_load16(BT + (size_t)(n0 + cb*8 + arow)*DIM + k0 + acol, &Bs[cb * 512]);
    }
    if (isconv) {
      // fused fp32->bf16 A staging (replaces convert_x; bit-exact f2bf)
      #pragma unroll
      for (int t = 0; t < 2; t++) {
        const float4 v0 = *(const float4*)&Af[(size_t)(m0 + sr + t*64) * DIM + k0 + sk];
        const float4 v1 = *(const float4*)&Af[(size_t)(m0 + sr + t*64) * DIM + k0 + sk + 4];
        const float v[8] = {v0.x, v0.y, v0.z, v0.w, v1.x, v1.y, v1.z, v1.w};
        unsigned int ov[4];
        #pragma unroll
        for (int j = 0; j < 4; j++)
          ov[j] = (unsigned int)f2bf(v[2*j]) | ((unsigned int)f2bf(v[2*j+1]) << 16);
        *(uint4*)&As[(sr + t*64) * 64 + swk] = *(const uint4*)ov;
      }
    } else if (bnscale) {
      // fused BN+relu A staging (reg-staged; swizzled ds_write)
      const uint4 x0 = *(const uint4*)&Ab[(size_t)(m0 + sr)      * DIM + k0 + sk];
      const uint4 x1 = *(const uint4*)&Ab[(size_t)(m0 + sr + 64) * DIM + k0 + sk];
      const float4 sc0 = *(const float4*)&bnscale[k0 + sk];
      const float4 sc1 = *(const float4*)&bnscale[k0 + sk + 4];
      const float4 sh0 = *(const float4*)&bnshift[k0 + sk];
      const float4 sh1 = *(const float4*)&bnshift[k0 + sk + 4];
      const float scv[8] = {sc0.x, sc0.y, sc0.z, sc0.w, sc1.x, sc1.y, sc1.z, sc1.w};
      const float shv[8] = {sh0.x, sh0.y, sh0.z, sh0.w, sh1.x, sh1.y, sh1.z, sh1.w};
      const uint4 xs[2] = {x0, x1};
      #pragma unroll
      for (int t = 0; t < 2; t++) {
        const unsigned int* xp = (const unsigned int*)&xs[t];
        unsigned int ov[4];
        #pragma unroll
        for (int j = 0; j < 4; j++) {
          const float a = bf2f((unsigned short)(xp[j] & 0xffffu));
          const float b = bf2f((unsigned short)(xp[j] >> 16));
          const float ya = fmaxf(0.f, a * scv[2*j]     + shv[2*j]);
          const float yb = fmaxf(0.f, b * scv[2*j + 1] + shv[2*j + 1]);
          ov[j] = (unsigned int)f2bf(ya) | ((unsigned int)f2bf(yb) << 16);
        }
        *(uint4*)&As[(sr + t*64) * 64 + swk] = *(const uint4*)ov;
      }
    } else {
      #pragma unroll
      for (int t = 0; t < 2; t++) {    // A raw: async path (pre-swizzled source)
        const int cb = wv * 2 + t;
        async_load16(Ab + (size_t)(m0 + cb*8 + arow)*DIM + k0 + acol, &As[cb * 512]);
      }
    }
    __syncthreads();
    #pragma unroll
    for (int kk = 0; kk < 64; kk += 32) {
      const int cg = (kk >> 3) + q;                 // data colgrp 0..7
      const int po = ((cg ^ rx) * 8);               // physical bf16 offset
      short8 aF[4], bF[4];
      #pragma unroll
      for (int mt = 0; mt < 4; mt++)
        aF[mt] = *(const short8*)&As[(wr + mt*16 + c16) * 64 + po];
      #pragma unroll
      for (int nt = 0; nt < 4; nt++)
        bF[nt] = *(const short8*)&Bs[(wc + nt*16 + c16) * 64 + po];
      #pragma unroll
      for (int mt = 0; mt < 4; mt++)
        #pragma unroll
        for (int nt = 0; nt < 4; nt++)
          acc[mt][nt] = __builtin_amdgcn_mfma_f32_16x16x32_bf16(aF[mt], bF[nt], acc[mt][nt], 0, 0, 0);
    }
    __syncthreads();
  }
  // C/D layout (verified m89/m91): col = lane&15, row = (lane>>4)*4 + reg
  #pragma unroll
  for (int mt = 0; mt < 4; mt++) {
    #pragma unroll
    for (int nt = 0; nt < 4; nt++) {
      const int col = n0 + wc + nt*16 + c16;
      #pragma unroll
      for (int r = 0; r < 4; r++) {
        const int row = m0 + wr + mt*16 + q*4 + r;
        C[(size_t)row * DIM + col] = f2bf(acc[mt][nt][r]);
      }
    }
  }
  // fused logits: this wave's head covers cols [wc, wc+64) of this n-tile
  const int head = 4 * n_blk + (wc >> 6);
  float as_[4], ad_[4];
  #pragma unroll
  for (int nt = 0; nt < 4; nt++) {
    const int d2 = nt * 16 + c16;                // 0..63 within head
    as_[nt] = asrc[head * DHEAD + d2];
    ad_[nt] = adst[head * DHEAD + d2];
  }
  #pragma unroll
  for (int mt = 0; mt < 4; mt++) {
    #pragma unroll
    for (int r = 0; r < 4; r++) {
      float ss = 0.f, sd = 0.f;
      #pragma unroll
      for (int nt = 0; nt < 4; nt++) {
        ss += acc[mt][nt][r] * as_[nt];
        sd += acc[mt][nt][r] * ad_[nt];
      }
      #pragma unroll
      for (int msk = 1; msk <= 8; msk <<= 1) {   // reduce over the 16 c16 lanes
        ss += __shfl_xor(ss, msk, 64);
        sd += __shfl_xor(sd, msk, 64);
      }
      if (c16 == 0) {
        const int row = m0 + wr + mt*16 + q*4 + r;
        als[row * NH + head] = ss;
        ald[row * NH + head] = sd;
      }
    }
  }
}

// ---------------- GAT aggregate r23 (r21 structure: unroll-2 node loop, ps/pq partials) ----------------
__global__ __launch_bounds__(512, 4) void gat_agg_r23(const unsigned short* __restrict__ Hm,
    const float* __restrict__ als, const float* __restrict__ ald,
    const int* __restrict__ offs, const int* __restrict__ csrc,
    const float* __restrict__ bconv, unsigned short* __restrict__ Xout,
    float* __restrict__ ps, float* __restrict__ pq)
{
  __shared__ float red[8][1024];
  const int wv = threadIdx.x >> 6, lane = threadIdx.x & 63;
  const int hd = lane >> 3;            // head owning dims [lane*8, lane*8+8)
  const int hp = lane & 7;             // head in the parallel-logit mapping
  const int slot = lane >> 3;          // edge slot in the parallel-logit mapping
  const float4 bA = ((const float4*)(bconv + (size_t)lane * 8))[0];
  const float4 bB = ((const float4*)(bconv + (size_t)lane * 8))[1];
  const float barr[8] = {bA.x, bA.y, bA.z, bA.w, bB.x, bB.y, bB.z, bB.w};
  float cs[8] = {}, cq[8] = {};

  #pragma unroll 2
  for (int i = 0; i < 4; i++) {
    const int node = blockIdx.x * AGG_NODES + wv * 4 + i;
    const int e0 = offs[node], e1 = offs[node + 1];
    const int deg = e1 - e0;
    float acc[8] = {};
    float zinv;

    if (deg <= 8) {
      // ---- hot path ----
      const float aldp = ald[node * NH + hp];
      const int myS = csrc[e0 + ((lane < deg) ? lane : 0)];
      const int s_slot = __shfl(myS, slot, 64);
      float lg = als[s_slot * NH + hp] + aldp;
      lg = lg > 0.f ? lg : 0.2f * lg;
      const float lgv = (slot < deg) ? lg : -1e30f;
      float mx = fmaxf(lgv, __shfl_xor(lgv, 8, 64));
      mx = fmaxf(mx, __shfl_xor(mx, 16, 64));
      mx = fmaxf(mx, __shfl_xor(mx, 32, 64));
      const float w = __expf(lgv - mx);            // pad slots: 0
      float z = w + __shfl_xor(w, 8, 64);
      z += __shfl_xor(z, 16, 64);
      z += __shfl_xor(z, 32, 64);
      zinv = 1.f / (__shfl(z, hd, 64) + 1e-16f);

      #pragma unroll
      for (int g = 0; g < 2; g++) {
        const int b = g * 4;
        if (b < deg) {                              // wave-uniform guard
          const int k1 = (b+1 < deg) ? b+1 : 0;
          const int k2 = (b+2 < deg) ? b+2 : 0;
          const int k3 = (b+3 < deg) ? b+3 : 0;
          const int s0 = __shfl(myS, b,  64);
          const int s1 = __shfl(myS, k1, 64);
          const int s2 = __shfl(myS, k2, 64);
          const int s3 = __shfl(myS, k3, 64);
          const uint4 h0v = *(const uint4*)&Hm[(size_t)s0 * DIM + lane * 8];
          const uint4 h1v = *(const uint4*)&Hm[(size_t)s1 * DIM + lane * 8];
          const uint4 h2v = *(const uint4*)&Hm[(size_t)s2 * DIM + lane * 8];
          const uint4 h3v = *(const uint4*)&Hm[(size_t)s3 * DIM + lane * 8];
          const float w0 = __shfl(w, (b+0)*8 + hd, 64);
          const float w1 = __shfl(w, (b+1)*8 + hd, 64);  // 0 if b+1 >= deg
          const float w2 = __shfl(w, (b+2)*8 + hd, 64);
          const float w3 = __shfl(w, (b+3)*8 + hd, 64);
          const unsigned int* p0 = (const unsigned int*)&h0v;
          const unsigned int* p1 = (const unsigned int*)&h1v;
          const unsigned int* p2 = (const unsigned int*)&h2v;
          const unsigned int* p3 = (const unsigned int*)&h3v;
          #pragma unroll
          for (int j = 0; j < 4; j++) {
            acc[2*j]   += w0 * bf2f((unsigned short)(p0[j] & 0xffffu))
                        + w1 * bf2f((unsigned short)(p1[j] & 0xffffu))
                        + w2 * bf2f((unsigned short)(p2[j] & 0xffffu))
                        + w3 * bf2f((unsigned short)(p3[j] & 0xffffu));
            acc[2*j+1] += w0 * bf2f((unsigned short)(p0[j] >> 16))
                        + w1 * bf2f((unsigned short)(p1[j] >> 16))
                        + w2 * bf2f((unsigned short)(p2[j] >> 16))
                        + w3 * bf2f((unsigned short)(p3[j] >> 16));
          }
        }
      }
    } else if (deg <= 64) {
      // ---- mid path (rare, ~0.6%) ----
      const float aldp = ald[node * NH + hp];
      const int myS = (lane < deg) ? csrc[e0 + lane] : 0;
      const int nr = (deg + 7) >> 3;
      float lgsto[8];
      #pragma unroll
      for (int r = 0; r < 8; r++) {
        if (r < nr) {
          const int k = r * 8 + slot;
          const int s = __shfl(myS, k & 63, 64);
          float lg = als[s * NH + hp] + aldp;
          lg = lg > 0.f ? lg : 0.2f * lg;
          lgsto[r] = (k < deg) ? lg : -1e30f;
        } else lgsto[r] = -1e30f;
      }
      float m = lgsto[0];
      #pragma unroll
      for (int r = 1; r < 8; r++) m = fmaxf(m, lgsto[r]);
      m = fmaxf(m, __shfl_xor(m, 8, 64));
      m = fmaxf(m, __shfl_xor(m, 16, 64));
      m = fmaxf(m, __shfl_xor(m, 32, 64));
      float z = 0.f;
      float wsto[8];
      #pragma unroll
      for (int r = 0; r < 8; r++) {
        if (r < nr) {
          const float w = __expf(lgsto[r] - m);
          wsto[r] = w; z += w;
        } else wsto[r] = 0.f;
      }
      z += __shfl_xor(z, 8, 64);
      z += __shfl_xor(z, 16, 64);
      z += __shfl_xor(z, 32, 64);
      zinv = 1.f / (__shfl(z, hd, 64) + 1e-16f);

      int sn = __shfl(myS, 0, 64);
      uint4 hv = *(const uint4*)&Hm[(size_t)sn * DIM + lane * 8];
      #pragma unroll
      for (int r = 0; r < 8; r++) {
        if (r * 8 < deg) {
          const int kmax = (deg - r * 8 < 8) ? (deg - r * 8) : 8;
          for (int kk = 0; kk < kmax; kk++) {
            const uint4 hcur = hv;
            const int k = r * 8 + kk;
            if (k + 1 < deg) {
              const int s2 = __shfl(myS, (k + 1) & 63, 64);
              hv = *(const uint4*)&Hm[(size_t)s2 * DIM + lane * 8];
            }
            const float w = __shfl(wsto[r], (kk << 3) + hd, 64);
            const unsigned int* hpx = (const unsigned int*)&hcur;
            #pragma unroll
            for (int j = 0; j < 4; j++) {
              acc[2*j]   += w * bf2f((unsigned short)(hpx[j] & 0xffffu));
              acc[2*j+1] += w * bf2f((unsigned short)(hpx[j] >> 16));
            }
          }
        }
      }
    } else {
      // ---- generic fallback (deg > 64): online softmax ----
      const float aldv = ald[node * NH + hd];
      float m = -1e30f, z = 0.f;
      for (int e = e0; e < e1; e++) {
        const int s = csrc[e];
        float lg = als[s * NH + hd] + aldv;
        lg = lg > 0.f ? lg : 0.2f * lg;
        const float mn = fmaxf(m, lg);
        const float sf = __expf(m - mn);
        const float w  = __expf(lg - mn);
        z = z * sf + w;
        const uint4 hv = *(const uint4*)&Hm[(size_t)s * DIM + lane * 8];
        const unsigned int* hpx = (const unsigned int*)&hv;
        #pragma unroll
        for (int j = 0; j < 4; j++) {
          acc[2*j]   = acc[2*j]   * sf + w * bf2f((unsigned short)(hpx[j] & 0xffffu));
          acc[2*j+1] = acc[2*j+1] * sf + w * bf2f((unsigned short)(hpx[j] >> 16));
        }
        m = mn;
      }
      zinv = 1.f / (z + 1e-16f);
    }

    unsigned int ov[4];
    #pragma unroll
    for (int j = 0; j < 4; j++) {
      const unsigned short b0 = f2bf(acc[2*j] * zinv + barr[2*j]);
      const unsigned short b1 = f2bf(acc[2*j+1] * zinv + barr[2*j+1]);
      ov[j] = (unsigned int)b0 | ((unsigned int)b1 << 16);
      const float y0 = bf2f(b0), y1 = bf2f(b1);   // rounded values, matching bn_stats-on-xbuf
      cs[2*j]   += y0; cq[2*j]   += y0 * y0;
      cs[2*j+1] += y1; cq[2*j+1] += y1 * y1;
    }
    *(uint4*)&Xout[(size_t)node * DIM + lane * 8] = *(const uint4*)ov;
  }
  #pragma unroll
  for (int j = 0; j < 8; j++) {
    red[wv][lane * 8 + j] = cs[j];
    red[wv][512 + lane * 8 + j] = cq[j];
  }
  __syncthreads();
  const int t = threadIdx.x;          // 0..511 -> one column each
  float s = 0.f, q = 0.f;
  #pragma unroll
  for (int w = 0; w < 8; w++) {
    s += red[w][t];
    q += red[w][512 + t];
  }
  ps[(size_t)blockIdx.x * 512 + t] = s;
  pq[(size_t)blockIdx.x * 512 + t] = q;
}

// ---------------- BN reduce+finalize: one block per column ----------------
__global__ __launch_bounds__(256) void bn_reduce_r23(const float* __restrict__ ps, const float* __restrict__ pq,
                                                     const float* __restrict__ gamma, const float* __restrict__ beta,
                                                     float* __restrict__ scale, float* __restrict__ shift)
{
  __shared__ float rs[256], rq[256];
  const int c = blockIdx.x;           // 0..511
  const int t = threadIdx.x;
  float s = 0.f, q = 0.f;
  for (int b = t; b < AGG_BLOCKS; b += 256) {
    s += ps[(size_t)b * 512 + c];
    q += pq[(size_t)b * 512 + c];
  }
  rs[t] = s; rq[t] = q;
  __syncthreads();
  for (int o = 128; o > 0; o >>= 1) {
    if (t < o) { rs[t] += rs[t + o]; rq[t] += rq[t + o]; }
    __syncthreads();
  }
  if (t == 0) {
    const float inv = 1.0f / (float)N_NODES;
    const float mean = rs[0] * inv;
    float var = rq[0] * inv - mean * mean;
    var = fmaxf(var, 0.f);
    const float rsq = rsqrtf(var + 1e-5f);
    const float sc = gamma[c] * rsq;
    scale[c] = sc;
    shift[c] = beta[c] - mean * sc;
  }
}

// ---------------- final head: out[n] = relu(bn(X[n,:])) . Wl + bl ----------------
__global__ __launch_bounds__(256) void final_head_r23(const unsigned short* __restrict__ X,
    const float* __restrict__ scale, const float* __restrict__ shift,
    const float* __restrict__ wl, const float* __restrict__ blp,
    float* __restrict__ out)
{
  const int wv = threadIdx.x >> 6, lane = threadIdx.x & 63;
  const int node = blockIdx.x * 4 + wv;
  const uint4 xv = *(const uint4*)&X[(size_t)node * DIM + lane * 8];
  const unsigned int* xp = (const unsigned int*)&xv;
  const int c0 = lane * 8;
  float s = 0.f;
  #pragma unroll
  for (int i = 0; i < 4; i++) {
    const float a0 = bf2f((unsigned short)(xp[i] & 0xffffu));
    const float a1 = bf2f((unsigned short)(xp[i] >> 16));
    const float y0 = fmaxf(0.f, a0 * scale[c0 + 2*i]     + shift[c0 + 2*i]);
    const float y1 = fmaxf(0.f, a1 * scale[c0 + 2*i + 1] + shift[c0 + 2*i + 1]);
    s += y0 * wl[c0 + 2*i] + y1 * wl[c0 + 2*i + 1];
  }
  #pragma unroll
  for (int msk = 32; msk >= 1; msk >>= 1) s += __shfl_xor(s, msk, 64);
  if (lane == 0) out[node] = s + blp[0];
}

extern "C" void kernel_launch(void* const* d_in, const int* in_sizes, int n_in,
                              void* d_out, int out_size, void* d_ws, size_t ws_size,
                              hipStream_t stream)
{
  const float* x_in  = (const float*)d_in[0];
  const int*   ei    = (const int*)d_in[1];
  const float* Ws    = (const float*)d_in[2];
  const float* Asrc  = (const float*)d_in[3];
  const float* Adst  = (const float*)d_in[4];
  const float* Bconv = (const float*)d_in[5];
  const float* Gamma = (const float*)d_in[6];
  const float* Beta  = (const float*)d_in[7];
  const float* Wl    = (const float*)d_in[8];
  const float* bl    = (const float*)d_in[9];
  float* out = (float*)d_out;

  char* ws = (char*)d_ws;
  size_t off = 0;
  auto alloc = [&](size_t b) { char* p = ws + off; off += (b + 255) & ~(size_t)255; return p; };
  unsigned short* xbuf = (unsigned short*)alloc((size_t)N_NODES * DIM * 2);
  unsigned short* hbuf = (unsigned short*)alloc((size_t)N_NODES * DIM * 2);
  unsigned short* WT   = (unsigned short*)alloc((size_t)NLAYERS * DIM * DIM * 2);
  float* als   = (float*)alloc((size_t)N_NODES * NH * 4);
  float* ald   = (float*)alloc((size_t)N_NODES * NH * 4);
  int* eidx    = (int*)alloc((size_t)2 * NE * 4);
  int* counts  = (int*)alloc((size_t)N_NODES * 4);
  int* offs    = (int*)alloc(((size_t)N_NODES + 1) * 4);
  int* cursor  = (int*)alloc((size_t)N_NODES * 4);
  int* csrc    = (int*)alloc((size_t)ETOT * 4);
  float* ps    = (float*)alloc((size_t)AGG_BLOCKS * 512 * 4);
  float* pq    = (float*)alloc((size_t)AGG_BLOCKS * 512 * 4);
  float* scale = (float*)alloc(512 * 4);
  float* shift = (float*)alloc(512 * 4);

  transpose_w_r23<<<dim3(16, 16, 5), 256, 0, stream>>>(Ws, WT);
  repack_edges_r23<<<(2 * NE) / 256, 256, 0, stream>>>(ei, eidx);
  init_counts_r23<<<N_NODES / 256, 256, 0, stream>>>(counts);
  hist_dst_r23<<<NE / 256, 256, 0, stream>>>(eidx, counts);
  scan_kernel_r23<<<1, 1024, 0, stream>>>(counts, offs, cursor);
  scatter_edges_r23<<<ETOT / 256, 256, 0, stream>>>(eidx, cursor, csrc);

  for (int l = 0; l < NLAYERS; l++) {
    gemm_bt_r23<<<768, 512, 0, stream>>>(
        (l == 0) ? x_in : nullptr, (l == 0) ? nullptr : xbuf,
        WT + (size_t)l * DIM * DIM,
        Asrc + l * NH * DHEAD, Adst + l * NH * DHEAD,
        (l == 0) ? nullptr : scale, (l == 0) ? nullptr : shift,
        hbuf, als, ald, (l == 0) ? 0 : 1);
    gat_agg_r23<<<AGG_BLOCKS, 512, 0, stream>>>(hbuf, als, ald, offs, csrc,
                                                Bconv + l * DIM, xbuf, ps, pq);
    bn_reduce_r23<<<512, 256, 0, stream>>>(ps, pq, Gamma + l * DIM, Beta + l * DIM, scale, shift);
  }
  final_head_r23<<<N_NODES / 4, 256, 0, stream>>>(xbuf, scale, shift, Wl, bl, out);
}